// Round 2
// baseline (170.813 us; speedup 1.0000x reference)
//
#include <hip/hip_runtime.h>
#include <hip/hip_bf16.h>

#define Bn 64
#define Cn 128
#define Tn 2048
#define Fn 5
#define Nn 640
#define TCHUNK 128

typedef __attribute__((ext_vector_type(8))) short bf16x8;
typedef __attribute__((ext_vector_type(4))) float f32x4;

// round-to-nearest-even f32 -> bf16 (finite inputs)
__device__ __forceinline__ short f2bf(float f) {
    union { float f; unsigned u; } v; v.f = f;
    unsigned r = (v.u + 0x7fffu + ((v.u >> 16) & 1u)) >> 16;
    return (short)r;
}

// XOR swizzle: spreads rows across bank-quads (G4). row in [0,128), bytecol in [0,256)
__device__ __forceinline__ int swz_off(int row, int bytecol) {
    return (row * 256 + bytecol) ^ ((row & 7) << 4);
}

__device__ __forceinline__ const float* pick_band(const float* d0, const float* d1,
                                                  const float* d2, const float* d3,
                                                  const float* d4, int f) {
    return (f == 0) ? d0 : (f == 1) ? d1 : (f == 2) ? d2 : (f == 3) ? d3 : d4;
}

// ---------------- K1: partial Gram over a T-slice ----------------
// grid = 320*Q blocks, 512 threads. block -> (b, f, q). Writes partial Gram
// (128x128 f32) and partial row sums (128 f32) to workspace.
__global__ __launch_bounds__(512, 4)
void gram_kernel(const float* __restrict__ d0, const float* __restrict__ d1,
                 const float* __restrict__ d2, const float* __restrict__ d3,
                 const float* __restrict__ d4,
                 float* __restrict__ wsG, float* __restrict__ wsS, int Q)
{
    __shared__ short Xs[Cn * TCHUNK];   // 32 KB swizzled bf16 tile
    __shared__ float S_lds[Cn];

    const int tid = threadIdx.x;
    const int blk = blockIdx.x;
    const int bf = blk / Q;
    const int q  = blk - bf * Q;
    const int b = bf / Fn;
    const int f = bf - b * Fn;
    const int NC = 16 / Q;              // chunks of 128 samples in this slice

    const float* src = pick_band(d0, d1, d2, d3, d4, f)
                     + (size_t)b * Cn * Tn + (size_t)q * (Tn / Q);

    if (tid < Cn) S_lds[tid] = 0.0f;

    // staging mapping: thread covers rows (srow + 32i), 8 consecutive f32 at segment sseg
    const int srow = tid >> 4;          // 0..31
    const int sseg = tid & 15;          // 0..15

    // wave mapping: 8 waves in 4x2 grid, each owns a 32x64 tile of Q
    const int lane = tid & 63;
    const int w  = tid >> 6;
    const int wr = w >> 1;
    const int wc = w & 1;
    const int r0 = wr * 32;
    const int c0 = wc * 64;
    const int lg = lane >> 4;
    const int ll = lane & 15;

    f32x4 acc[2][4] = {};
    float psum[4] = {0.f, 0.f, 0.f, 0.f};

    float4 pf[8];
    auto issue = [&](int ch) {
        const float* cb = src + ch * TCHUNK;
        #pragma unroll
        for (int i = 0; i < 4; ++i) {
            const float* rp = cb + (size_t)(i * 32 + srow) * Tn + sseg * 8;
            pf[2 * i]     = *(const float4*)rp;
            pf[2 * i + 1] = *(const float4*)(rp + 4);
        }
    };

    issue(0);

    for (int ch = 0; ch < NC; ++ch) {
        // convert prefetched chunk -> LDS (waits on pf loads)
        #pragma unroll
        for (int i = 0; i < 4; ++i) {
            const int row = i * 32 + srow;
            float4 v0 = pf[2 * i], v1 = pf[2 * i + 1];
            psum[i] += v0.x + v0.y + v0.z + v0.w + v1.x + v1.y + v1.z + v1.w;
            bf16x8 h;
            h[0]=f2bf(v0.x); h[1]=f2bf(v0.y); h[2]=f2bf(v0.z); h[3]=f2bf(v0.w);
            h[4]=f2bf(v1.x); h[5]=f2bf(v1.y); h[6]=f2bf(v1.z); h[7]=f2bf(v1.w);
            *(bf16x8*)((char*)Xs + swz_off(row, sseg * 16)) = h;
        }
        // prefetch next chunk (in flight across MFMA phase)
        if (ch + 1 < NC) issue(ch + 1);
        __syncthreads();

        #pragma unroll
        for (int ks = 0; ks < 4; ++ks) {
            bf16x8 afr[2], bfr[4];
            #pragma unroll
            for (int m = 0; m < 2; ++m) {
                const int row = r0 + m * 16 + ll;
                afr[m] = *(const bf16x8*)((const char*)Xs + swz_off(row, ks * 64 + lg * 16));
            }
            #pragma unroll
            for (int n = 0; n < 4; ++n) {
                const int col = c0 + n * 16 + ll;
                bfr[n] = *(const bf16x8*)((const char*)Xs + swz_off(col, ks * 64 + lg * 16));
            }
            #pragma unroll
            for (int m = 0; m < 2; ++m)
                #pragma unroll
                for (int n = 0; n < 4; ++n)
                    acc[m][n] = __builtin_amdgcn_mfma_f32_16x16x32_bf16(afr[m], bfr[n], acc[m][n], 0, 0, 0);
        }
        __syncthreads();
    }

    // partial row sums
    #pragma unroll
    for (int i = 0; i < 4; ++i)
        atomicAdd(&S_lds[i * 32 + srow], psum[i]);
    __syncthreads();
    if (tid < Cn) wsS[(size_t)blk * Cn + tid] = S_lds[tid];

    // partial Gram
    float* G = wsG + (size_t)blk * (Cn * Cn);
    #pragma unroll
    for (int m = 0; m < 2; ++m)
      #pragma unroll
      for (int e = 0; e < 4; ++e) {
          const int row = r0 + m * 16 + lg * 4 + e;
          #pragma unroll
          for (int n = 0; n < 4; ++n) {
              const int col = c0 + n * 16 + ll;
              G[row * Cn + col] = acc[m][n][e];
          }
      }
}

// ---------------- K2: finalize ----------------
// grid = 320 blocks (b,f), 256 threads. Sums Q partials, computes var/corr/
// normalization, writes the FULL 128x640 row-stripe of A_norm (zeros included),
// node_features, bandpowers. No separate memset needed.
__global__ __launch_bounds__(256)
void finalize_kernel(const float* __restrict__ wsG, const float* __restrict__ wsS,
                     float* __restrict__ out, int Q)
{
    __shared__ float G[Cn * Cn];        // 64 KB
    __shared__ float mrow[Cn], ivrow[Cn], dinv_s[Cn], Dsum[Cn];

    const int tid = threadIdx.x;
    const int bf = blockIdx.x;
    const int b = bf / Fn;
    const int f = bf - b * Fn;

    // sum Q partial Grams -> LDS
    const float* P0 = wsG + (size_t)bf * Q * (Cn * Cn);
    for (int e = 0; e < 16; ++e) {
        const int idx = e * 1024 + tid * 4;
        float4 s = *(const float4*)(P0 + idx);
        for (int qq = 1; qq < Q; ++qq) {
            float4 t = *(const float4*)(P0 + (size_t)qq * (Cn * Cn) + idx);
            s.x += t.x; s.y += t.y; s.z += t.z; s.w += t.w;
        }
        *(float4*)&G[idx] = s;
    }

    float S = 0.f;
    if (tid < Cn) {
        const float* Sp = wsS + (size_t)bf * Q * Cn;
        for (int qq = 0; qq < Q; ++qq) S += Sp[qq * Cn + tid];
        Dsum[tid] = 0.f;
    }
    __syncthreads();

    if (tid < Cn) {
        const float mu = S * (1.0f / Tn);
        float var = (G[tid * (Cn + 1)] - (float)Tn * mu * mu) * (1.0f / (Tn - 1));
        var = var < 0.f ? 0.f : var;
        const float sd = sqrtf(var);
        mrow[tid]  = mu;
        ivrow[tid] = 1.0f / (sd + 1e-8f);
        const size_t ofs = (size_t)Bn * Nn * Nn;
        out[ofs + (size_t)b * Nn + f * Cn + tid] = var;                      // node_features
        out[ofs + (size_t)Bn * Nn + ((size_t)b * Cn + tid) * Fn + f] = var;  // bandpowers
    }
    __syncthreads();

    // pass 1: a = 0.5*(spa + |corr|), in-place into G; accumulate row sums
    const float inv = 1.0f / (Tn - 1);
    for (int e = 0; e < 64; ++e) {
        const int idx = e * 256 + tid;
        const int row = idx >> 7;
        const int col = idx & 127;
        const float qv = G[idx];
        float c = fabsf((qv - (float)Tn * mrow[row] * mrow[col]) * ivrow[row] * ivrow[col] * inv);
        c = (row == col) ? 1.0f : c;
        const int d = row > col ? row - col : col - row;
        const float spa = (d >= 1 && d <= 3) ? 1.0f : 0.0f;
        const float a = 0.5f * (spa + c);
        G[idx] = a;
        // row is uniform across each 64-lane segment (64-aligned run within a 128-col row)
        float s = a;
        s += __shfl_xor(s, 1);
        s += __shfl_xor(s, 2);
        s += __shfl_xor(s, 4);
        s += __shfl_xor(s, 8);
        s += __shfl_xor(s, 16);
        s += __shfl_xor(s, 32);
        if ((tid & 63) == 0) atomicAdd(&Dsum[row], s);
    }
    __syncthreads();

    if (tid < Cn) dinv_s[tid] = rsqrtf(Dsum[tid] + 1e-8f);
    __syncthreads();

    // pass 2: write full 128x640 stripe (diag block scaled, rest zeros)
    float* Ob = out + (size_t)b * Nn * Nn;
    const int fc = f * Cn;
    for (int e = 0; e < 80; ++e) {
        const int idx4 = e * 1024 + tid * 4;
        const int row = idx4 / Nn;
        const int col = idx4 - row * Nn;
        const int cl = col - fc;
        float4 v;
        if (cl >= 0 && cl < Cn) {
            const float dr = dinv_s[row];
            v.x = dr * G[row * Cn + cl]     * dinv_s[cl];
            v.y = dr * G[row * Cn + cl + 1] * dinv_s[cl + 1];
            v.z = dr * G[row * Cn + cl + 2] * dinv_s[cl + 2];
            v.w = dr * G[row * Cn + cl + 3] * dinv_s[cl + 3];
        } else {
            v.x = 0.f; v.y = 0.f; v.z = 0.f; v.w = 0.f;
        }
        *(float4*)(Ob + (size_t)(fc + row) * Nn + col) = v;
    }
}

// ---------------- fallback: round-1 monolithic kernel (known good) ----------------
__global__ __launch_bounds__(512)
void strg_fallback(const float* __restrict__ d0, const float* __restrict__ d1,
                   const float* __restrict__ d2, const float* __restrict__ d3,
                   const float* __restrict__ d4, float* __restrict__ out)
{
    __shared__ short  Xs[Cn * TCHUNK];
    __shared__ float  S_lds[Cn];
    __shared__ float  diag[Cn];
    __shared__ float  mrow[Cn];
    __shared__ float  ivrow[Cn];
    __shared__ float  D_lds[Cn];
    __shared__ float  dinv[Cn];

    const int tid = threadIdx.x;
    const int bfid = blockIdx.x;
    const int b = bfid / Fn;
    const int f = bfid - b * Fn;

    const float* src = pick_band(d0, d1, d2, d3, d4, f) + (size_t)b * Cn * Tn;

    if (tid < Cn) { S_lds[tid] = 0.0f; D_lds[tid] = 0.0f; }

    const int srow = tid >> 4;
    const int sseg = tid & 15;
    const int lane = tid & 63;
    const int w  = tid >> 6;
    const int wr = w >> 1;
    const int wc = w & 1;
    const int r0 = wr * 32;
    const int c0 = wc * 64;
    const int lg = lane >> 4;
    const int ll = lane & 15;

    f32x4 acc[2][4] = {};
    float psum[4] = {0.f, 0.f, 0.f, 0.f};

    for (int ch = 0; ch < 16; ++ch) {
        const float* cb = src + ch * TCHUNK;
        #pragma unroll
        for (int i = 0; i < 4; ++i) {
            const int row = i * 32 + srow;
            const float* rp = cb + (size_t)row * Tn + sseg * 8;
            float4 v0 = *(const float4*)rp;
            float4 v1 = *(const float4*)(rp + 4);
            psum[i] += v0.x + v0.y + v0.z + v0.w + v1.x + v1.y + v1.z + v1.w;
            bf16x8 h;
            h[0]=f2bf(v0.x); h[1]=f2bf(v0.y); h[2]=f2bf(v0.z); h[3]=f2bf(v0.w);
            h[4]=f2bf(v1.x); h[5]=f2bf(v1.y); h[6]=f2bf(v1.z); h[7]=f2bf(v1.w);
            *(bf16x8*)((char*)Xs + swz_off(row, sseg * 16)) = h;
        }
        __syncthreads();
        #pragma unroll
        for (int ks = 0; ks < 4; ++ks) {
            bf16x8 afr[2], bfr[4];
            #pragma unroll
            for (int m = 0; m < 2; ++m)
                afr[m] = *(const bf16x8*)((const char*)Xs + swz_off(r0 + m * 16 + ll, ks * 64 + lg * 16));
            #pragma unroll
            for (int n = 0; n < 4; ++n)
                bfr[n] = *(const bf16x8*)((const char*)Xs + swz_off(c0 + n * 16 + ll, ks * 64 + lg * 16));
            #pragma unroll
            for (int m = 0; m < 2; ++m)
                #pragma unroll
                for (int n = 0; n < 4; ++n)
                    acc[m][n] = __builtin_amdgcn_mfma_f32_16x16x32_bf16(afr[m], bfr[n], acc[m][n], 0, 0, 0);
        }
        __syncthreads();
    }

    #pragma unroll
    for (int i = 0; i < 4; ++i)
        atomicAdd(&S_lds[i * 32 + srow], psum[i]);

    #pragma unroll
    for (int m = 0; m < 2; ++m)
      #pragma unroll
      for (int n = 0; n < 4; ++n)
        #pragma unroll
        for (int e = 0; e < 4; ++e) {
            const int row = r0 + m * 16 + lg * 4 + e;
            const int col = c0 + n * 16 + ll;
            if (row == col) diag[row] = acc[m][n][e];
        }
    __syncthreads();

    if (tid < Cn) {
        const float S  = S_lds[tid];
        const float mu = S * (1.0f / Tn);
        float var = (diag[tid] - (float)Tn * mu * mu) * (1.0f / (Tn - 1));
        var = var < 0.f ? 0.f : var;
        const float sd = sqrtf(var);
        mrow[tid]  = mu;
        ivrow[tid] = 1.0f / (sd + 1e-8f);
        const size_t ofs = (size_t)Bn * Nn * Nn;
        out[ofs + (size_t)b * Nn + f * Cn + tid] = var;
        out[ofs + (size_t)Bn * Nn + ((size_t)b * Cn + tid) * Fn + f] = var;
    }
    __syncthreads();

    float mi[2][4], ii[2][4], mj[4], ij[4];
    #pragma unroll
    for (int m = 0; m < 2; ++m)
      #pragma unroll
      for (int e = 0; e < 4; ++e) {
          const int row = r0 + m * 16 + lg * 4 + e;
          mi[m][e] = mrow[row];
          ii[m][e] = ivrow[row];
      }
    #pragma unroll
    for (int n = 0; n < 4; ++n) {
        const int col = c0 + n * 16 + ll;
        mj[n] = mrow[col];
        ij[n] = ivrow[col];
    }

    auto ablk = [&](int m, int n, int e) -> float {
        const int row = r0 + m * 16 + lg * 4 + e;
        const int col = c0 + n * 16 + ll;
        float c = fabsf((acc[m][n][e] - (float)Tn * mi[m][e] * mj[n])
                        * ii[m][e] * ij[n] * (1.0f / (Tn - 1)));
        c = (row == col) ? 1.0f : c;
        const int d = row > col ? row - col : col - row;
        const float spa = (d >= 1 && d <= 3) ? 1.0f : 0.0f;
        return 0.5f * (spa + c);
    };

    #pragma unroll
    for (int m = 0; m < 2; ++m)
      #pragma unroll
      for (int e = 0; e < 4; ++e) {
          float s = 0.f;
          #pragma unroll
          for (int n = 0; n < 4; ++n) s += ablk(m, n, e);
          s += __shfl_xor(s, 1);
          s += __shfl_xor(s, 2);
          s += __shfl_xor(s, 4);
          s += __shfl_xor(s, 8);
          if (ll == 0) atomicAdd(&D_lds[r0 + m * 16 + lg * 4 + e], s);
      }
    __syncthreads();

    if (tid < Cn) dinv[tid] = rsqrtf(D_lds[tid] + 1e-8f);
    __syncthreads();

    float di[2][4], dj[4];
    #pragma unroll
    for (int m = 0; m < 2; ++m)
      #pragma unroll
      for (int e = 0; e < 4; ++e)
          di[m][e] = dinv[r0 + m * 16 + lg * 4 + e];
    #pragma unroll
    for (int n = 0; n < 4; ++n)
        dj[n] = dinv[c0 + n * 16 + ll];

    float* Ab = out + (size_t)b * Nn * Nn;
    const int fc = f * Cn;
    #pragma unroll
    for (int m = 0; m < 2; ++m)
      #pragma unroll
      for (int e = 0; e < 4; ++e) {
          const int row = r0 + m * 16 + lg * 4 + e;
          const size_t rowoff = (size_t)(fc + row) * Nn + fc;
          #pragma unroll
          for (int n = 0; n < 4; ++n) {
              const int col = c0 + n * 16 + ll;
              Ab[rowoff + col] = di[m][e] * ablk(m, n, e) * dj[n];
          }
      }
}

extern "C" void kernel_launch(void* const* d_in, const int* in_sizes, int n_in,
                              void* d_out, int out_size, void* d_ws, size_t ws_size,
                              hipStream_t stream) {
    const float* d0 = (const float*)d_in[0];
    const float* d1 = (const float*)d_in[1];
    const float* d2 = (const float*)d_in[2];
    const float* d3 = (const float*)d_in[3];
    const float* d4 = (const float*)d_in[4];
    float* out = (float*)d_out;

    int Q = 0;
    for (int cand = 4; cand >= 1; cand >>= 1) {
        size_t need = (size_t)320 * cand * (Cn * Cn + Cn) * sizeof(float);
        if (need <= ws_size) { Q = cand; break; }
    }

    if (Q > 0) {
        float* wsG = (float*)d_ws;
        float* wsS = wsG + (size_t)320 * Q * (Cn * Cn);
        gram_kernel<<<dim3(320 * Q), dim3(512), 0, stream>>>(d0, d1, d2, d3, d4, wsG, wsS, Q);
        finalize_kernel<<<dim3(320), dim3(256), 0, stream>>>(wsG, wsS, out, Q);
    } else {
        hipMemsetAsync(d_out, 0, (size_t)out_size * sizeof(float), stream);
        strg_fallback<<<dim3(320), dim3(512), 0, stream>>>(d0, d1, d2, d3, d4, out);
    }
}

// Round 3
// 115.120 us; speedup vs baseline: 1.4838x; 1.4838x over previous
//
#include <hip/hip_runtime.h>
#include <hip/hip_bf16.h>

#define Bn 64
#define Cn 128
#define Tn 2048
#define Fn 5
#define Nn 640
#define TCHUNK 128
#define NCHUNK 16
#define BUFBYTES (Cn * TCHUNK * 2)   // 32 KB per bf16 buffer

typedef __attribute__((ext_vector_type(8))) short bf16x8;
typedef __attribute__((ext_vector_type(4))) float f32x4;

// round-to-nearest-even f32 -> bf16 (finite inputs)
__device__ __forceinline__ short f2bf(float f) {
    union { float f; unsigned u; } v; v.f = f;
    unsigned r = (v.u + 0x7fffu + ((v.u >> 16) & 1u)) >> 16;
    return (short)r;
}

// XOR swizzle: 2-way max aliasing on ds_read_b128 column reads (G4)
__device__ __forceinline__ int swz_off(int row, int bytecol) {
    return (row * 256 + bytecol) ^ ((row & 7) << 4);
}

__device__ __forceinline__ const float* pick_band(const float* d0, const float* d1,
                                                  const float* d2, const float* d3,
                                                  const float* d4, int f) {
    return (f == 0) ? d0 : (f == 1) ? d1 : (f == 2) ? d2 : (f == 3) ? d3 : d4;
}

// Monolithic: one block per (b,f). Double-buffered LDS staging with RAW
// s_barrier (no vmcnt drain) so next-next-chunk global loads stay in flight
// across the per-chunk barrier (T3/T4 pattern). Epilogue writes the full
// 128x640 A_norm row-stripe (zeros outside the diagonal block) -> no memset.
__global__ __launch_bounds__(512, 4)
void strg_mono(const float* __restrict__ d0, const float* __restrict__ d1,
               const float* __restrict__ d2, const float* __restrict__ d3,
               const float* __restrict__ d4, float* __restrict__ out)
{
    __shared__ __align__(16) char smem[2 * BUFBYTES];   // bf16 dbuf; reused as f32 A-tile
    __shared__ float S_lds[Cn], diag[Cn], mrow[Cn], ivrow[Cn], Dsum[Cn], dinv_s[Cn];

    const int tid = threadIdx.x;
    const int bfid = blockIdx.x;
    const int b = bfid / Fn;
    const int f = bfid - b * Fn;
    const float* src = pick_band(d0, d1, d2, d3, d4, f) + (size_t)b * Cn * Tn;

    if (tid < Cn) { S_lds[tid] = 0.0f; Dsum[tid] = 0.0f; }

    // staging mapping: thread covers rows (srow + 32i), 8 consecutive f32 at segment sseg
    const int srow = tid >> 4;          // 0..31
    const int sseg = tid & 15;          // 0..15

    // wave mapping: 8 waves in 4x2 grid, each owns a 32x64 tile of the Gram
    const int lane = tid & 63;
    const int w  = tid >> 6;
    const int wr = w >> 1;
    const int wc = w & 1;
    const int r0 = wr * 32;
    const int c0 = wc * 64;
    const int lg = lane >> 4;
    const int ll = lane & 15;

    f32x4 acc[2][4] = {};
    float psum[4] = {0.f, 0.f, 0.f, 0.f};
    float4 pf[8];

    const float* tb0 = src + (size_t)srow * Tn + sseg * 8;

    auto issue = [&](int ch) {
        const float* cb = tb0 + ch * TCHUNK;
        #pragma unroll
        for (int i = 0; i < 4; ++i) {
            const float* rp = cb + (size_t)(i * 32) * Tn;
            pf[2 * i]     = *(const float4*)rp;
            pf[2 * i + 1] = *(const float4*)(rp + 4);
        }
    };
    auto convert_write = [&](int buf) {
        char* base = smem + buf * BUFBYTES;
        #pragma unroll
        for (int i = 0; i < 4; ++i) {
            const int row = i * 32 + srow;
            float4 v0 = pf[2 * i], v1 = pf[2 * i + 1];
            psum[i] += v0.x + v0.y + v0.z + v0.w + v1.x + v1.y + v1.z + v1.w;
            bf16x8 h;
            h[0]=f2bf(v0.x); h[1]=f2bf(v0.y); h[2]=f2bf(v0.z); h[3]=f2bf(v0.w);
            h[4]=f2bf(v1.x); h[5]=f2bf(v1.y); h[6]=f2bf(v1.z); h[7]=f2bf(v1.w);
            *(bf16x8*)(base + swz_off(row, sseg * 16)) = h;
        }
    };
    auto mfma_phase = [&](int buf) {
        const char* base = smem + buf * BUFBYTES;
        #pragma unroll
        for (int ks = 0; ks < 4; ++ks) {
            bf16x8 afr[2], bfr[4];
            #pragma unroll
            for (int m = 0; m < 2; ++m)
                afr[m] = *(const bf16x8*)(base + swz_off(r0 + m * 16 + ll, ks * 64 + lg * 16));
            #pragma unroll
            for (int n = 0; n < 4; ++n)
                bfr[n] = *(const bf16x8*)(base + swz_off(c0 + n * 16 + ll, ks * 64 + lg * 16));
            #pragma unroll
            for (int m = 0; m < 2; ++m)
                #pragma unroll
                for (int n = 0; n < 4; ++n)
                    acc[m][n] = __builtin_amdgcn_mfma_f32_16x16x32_bf16(afr[m], bfr[n], acc[m][n], 0, 0, 0);
        }
    };

    // prologue: chunk0 staged, chunk1 in flight
    issue(0);
    convert_write(0);                 // compiler waits vmcnt for pf uses
    issue(1);
    asm volatile("s_waitcnt lgkmcnt(0)" ::: "memory");
    __builtin_amdgcn_s_barrier();
    __builtin_amdgcn_sched_barrier(0);

    for (int ch = 0; ch < NCHUNK; ++ch) {
        const int cur = ch & 1;
        mfma_phase(cur);                       // consume chunk ch
        if (ch + 1 < NCHUNK) {
            convert_write(cur ^ 1);            // chunk ch+1 (landed during MFMA)
            if (ch + 2 < NCHUNK) issue(ch + 2);// stays in flight ACROSS the barrier
        }
        asm volatile("s_waitcnt lgkmcnt(0)" ::: "memory");
        __builtin_amdgcn_s_barrier();          // raw: no vmcnt(0) drain
        __builtin_amdgcn_sched_barrier(0);
    }

    // ---- epilogue ----
    #pragma unroll
    for (int i = 0; i < 4; ++i)
        atomicAdd(&S_lds[i * 32 + srow], psum[i]);

    #pragma unroll
    for (int m = 0; m < 2; ++m)
      #pragma unroll
      for (int n = 0; n < 4; ++n)
        #pragma unroll
        for (int e = 0; e < 4; ++e) {
            const int row = r0 + m * 16 + lg * 4 + e;
            const int col = c0 + n * 16 + ll;
            if (row == col) diag[row] = acc[m][n][e];
        }
    __syncthreads();

    if (tid < Cn) {
        const float S  = S_lds[tid];
        const float mu = S * (1.0f / Tn);
        float var = (diag[tid] - (float)Tn * mu * mu) * (1.0f / (Tn - 1));
        var = var < 0.f ? 0.f : var;
        const float sd = sqrtf(var);
        mrow[tid]  = mu;
        ivrow[tid] = 1.0f / (sd + 1e-8f);
        const size_t ofs = (size_t)Bn * Nn * Nn;
        out[ofs + (size_t)b * Nn + f * Cn + tid] = var;                      // node_features
        out[ofs + (size_t)Bn * Nn + ((size_t)b * Cn + tid) * Fn + f] = var;  // bandpowers
    }
    __syncthreads();

    // a = 0.5*(spa + |corr|) -> LDS A-tile (reuse smem); accumulate row sums
    float* At = (float*)smem;
    {
        float mi[2][4], ii[2][4], mj[4], ij[4];
        #pragma unroll
        for (int m = 0; m < 2; ++m)
          #pragma unroll
          for (int e = 0; e < 4; ++e) {
              const int row = r0 + m * 16 + lg * 4 + e;
              mi[m][e] = mrow[row];
              ii[m][e] = ivrow[row];
          }
        #pragma unroll
        for (int n = 0; n < 4; ++n) {
            const int col = c0 + n * 16 + ll;
            mj[n] = mrow[col];
            ij[n] = ivrow[col];
        }
        const float inv = 1.0f / (Tn - 1);
        #pragma unroll
        for (int m = 0; m < 2; ++m)
          #pragma unroll
          for (int e = 0; e < 4; ++e) {
              const int row = r0 + m * 16 + lg * 4 + e;
              float s = 0.f;
              #pragma unroll
              for (int n = 0; n < 4; ++n) {
                  const int col = c0 + n * 16 + ll;
                  float c = fabsf((acc[m][n][e] - (float)Tn * mi[m][e] * mj[n])
                                  * ii[m][e] * ij[n] * inv);
                  c = (row == col) ? 1.0f : c;
                  const int d = row > col ? row - col : col - row;
                  const float spa = (d >= 1 && d <= 3) ? 1.0f : 0.0f;
                  const float a = 0.5f * (spa + c);
                  At[row * Cn + col] = a;
                  s += a;
              }
              s += __shfl_xor(s, 1);
              s += __shfl_xor(s, 2);
              s += __shfl_xor(s, 4);
              s += __shfl_xor(s, 8);
              if (ll == 0) atomicAdd(&Dsum[row], s);
          }
    }
    __syncthreads();

    if (tid < Cn) dinv_s[tid] = rsqrtf(Dsum[tid] + 1e-8f);
    __syncthreads();

    // write full 128x640 stripe of A_norm (coalesced float4, zeros outside block)
    float* Ob = out + (size_t)b * Nn * Nn;
    const int fc = f * Cn;
    for (int e = 0; e < 40; ++e) {
        const int idx4 = e * 2048 + tid * 4;
        const int row = idx4 / Nn;
        const int col = idx4 - row * Nn;
        const int cl = col - fc;
        float4 v = {0.f, 0.f, 0.f, 0.f};
        if (cl >= 0 && cl < Cn) {
            const float dr = dinv_s[row];
            v.x = dr * At[row * Cn + cl]     * dinv_s[cl];
            v.y = dr * At[row * Cn + cl + 1] * dinv_s[cl + 1];
            v.z = dr * At[row * Cn + cl + 2] * dinv_s[cl + 2];
            v.w = dr * At[row * Cn + cl + 3] * dinv_s[cl + 3];
        }
        *(float4*)(Ob + (size_t)(fc + row) * Nn + col) = v;
    }
}

extern "C" void kernel_launch(void* const* d_in, const int* in_sizes, int n_in,
                              void* d_out, int out_size, void* d_ws, size_t ws_size,
                              hipStream_t stream) {
    const float* d0 = (const float*)d_in[0];
    const float* d1 = (const float*)d_in[1];
    const float* d2 = (const float*)d_in[2];
    const float* d3 = (const float*)d_in[3];
    const float* d4 = (const float*)d_in[4];
    float* out = (float*)d_out;

    strg_mono<<<dim3(Bn * Fn), dim3(512), 0, stream>>>(d0, d1, d2, d3, d4, out);
}

// Round 4
// 108.158 us; speedup vs baseline: 1.5793x; 1.0644x over previous
//
#include <hip/hip_runtime.h>
#include <hip/hip_bf16.h>

#define Bn 64
#define Cn 128
#define Tn 2048
#define Fn 5
#define Nn 640
#define TCHUNK 64
#define NCHUNK 32
#define BUFBYTES (Cn * TCHUNK * 2)   // 16 KB per bf16 buffer

typedef __attribute__((ext_vector_type(8))) short bf16x8;
typedef __attribute__((ext_vector_type(4))) short bf16x4;
typedef __attribute__((ext_vector_type(4))) float f32x4;

// round-to-nearest-even f32 -> bf16 (finite inputs)
__device__ __forceinline__ short f2bf(float f) {
    union { float f; unsigned u; } v; v.f = f;
    unsigned r = (v.u + 0x7fffu + ((v.u >> 16) & 1u)) >> 16;
    return (short)r;
}

// bf16 row = 128 B; XOR-swizzle rows across 16B slots (G4). Bank period = 128 B.
__device__ __forceinline__ int swz(int row, int bytecol) {
    return (row * 128 + bytecol) ^ ((row & 7) << 4);
}

__device__ __forceinline__ const float* pick_band(const float* d0, const float* d1,
                                                  const float* d2, const float* d3,
                                                  const float* d4, int f) {
    return (f == 0) ? d0 : (f == 1) ? d1 : (f == 2) ? d2 : (f == 3) ? d3 : d4;
}

// One block per (b,f). Depth-3 register prefetch (2 named sets), convert-before-
// MFMA, raw s_barrier with lgkmcnt-only drain: global loads stay in flight
// across 2 full iterations before their vmcnt wait (T3/T4). Epilogue writes the
// full 128x640 A_norm stripe (no memset pass).
__global__ __launch_bounds__(512, 4)
void strg_mono(const float* __restrict__ d0, const float* __restrict__ d1,
               const float* __restrict__ d2, const float* __restrict__ d3,
               const float* __restrict__ d4, float* __restrict__ out)
{
    __shared__ __align__(16) char smem[Cn * Cn * 4];   // 64 KB: loop uses [0,32K) as dbuf; epilogue = f32 A-tile
    __shared__ float S_lds[Cn], diag[Cn], mrow[Cn], ivrow[Cn], Dsum[Cn], dinv_s[Cn];

    const int tid = threadIdx.x;
    const int bfid = blockIdx.x;
    const int b = bfid / Fn;
    const int f = bfid - b * Fn;
    const float* src = pick_band(d0, d1, d2, d3, d4, f) + (size_t)b * Cn * Tn;

    if (tid < Cn) { S_lds[tid] = 0.0f; Dsum[tid] = 0.0f; }

    // staging: thread covers rows (srow + 32i), one float4 (16 B) per row at seg sseg
    const int srow = tid >> 4;          // 0..31
    const int sseg = tid & 15;          // 0..15
    const float* tb0 = src + (size_t)srow * Tn + sseg * 4;

    // wave mapping: 8 waves in 4x2 grid, each owns a 32x64 tile of the Gram
    const int lane = tid & 63;
    const int w  = tid >> 6;
    const int wr = w >> 1;
    const int wc = w & 1;
    const int r0 = wr * 32;
    const int c0 = wc * 64;
    const int lg = lane >> 4;
    const int ll = lane & 15;

    f32x4 acc[2][4] = {};
    float psum[4] = {0.f, 0.f, 0.f, 0.f};
    float4 pfA[4], pfB[4];

    auto issueA = [&](int ch) {
        const float* cb = tb0 + ch * TCHUNK;
        #pragma unroll
        for (int i = 0; i < 4; ++i) pfA[i] = *(const float4*)(cb + (size_t)(i * 32) * Tn);
    };
    auto issueB = [&](int ch) {
        const float* cb = tb0 + ch * TCHUNK;
        #pragma unroll
        for (int i = 0; i < 4; ++i) pfB[i] = *(const float4*)(cb + (size_t)(i * 32) * Tn);
    };
    auto convA = [&](int buf) {
        char* base = smem + buf * BUFBYTES;
        #pragma unroll
        for (int i = 0; i < 4; ++i) {
            const int row = i * 32 + srow;
            float4 v = pfA[i];
            psum[i] += v.x + v.y + v.z + v.w;
            bf16x4 h; h[0] = f2bf(v.x); h[1] = f2bf(v.y); h[2] = f2bf(v.z); h[3] = f2bf(v.w);
            *(bf16x4*)(base + swz(row, sseg * 8)) = h;
        }
    };
    auto convB = [&](int buf) {
        char* base = smem + buf * BUFBYTES;
        #pragma unroll
        for (int i = 0; i < 4; ++i) {
            const int row = i * 32 + srow;
            float4 v = pfB[i];
            psum[i] += v.x + v.y + v.z + v.w;
            bf16x4 h; h[0] = f2bf(v.x); h[1] = f2bf(v.y); h[2] = f2bf(v.z); h[3] = f2bf(v.w);
            *(bf16x4*)(base + swz(row, sseg * 8)) = h;
        }
    };
    auto mfma_phase = [&](int buf) {
        const char* base = smem + buf * BUFBYTES;
        #pragma unroll
        for (int ks = 0; ks < 2; ++ks) {
            bf16x8 afr[2], bfr[4];
            #pragma unroll
            for (int m = 0; m < 2; ++m)
                afr[m] = *(const bf16x8*)(base + swz(r0 + m * 16 + ll, ks * 64 + lg * 16));
            #pragma unroll
            for (int n = 0; n < 4; ++n)
                bfr[n] = *(const bf16x8*)(base + swz(c0 + n * 16 + ll, ks * 64 + lg * 16));
            #pragma unroll
            for (int m = 0; m < 2; ++m)
                #pragma unroll
                for (int n = 0; n < 4; ++n)
                    acc[m][n] = __builtin_amdgcn_mfma_f32_16x16x32_bf16(afr[m], bfr[n], acc[m][n], 0, 0, 0);
        }
    };

    // prologue: chunk0 staged in buf0; chunk1 (B) and chunk2 (A) in flight
    issueA(0);
    issueB(1);
    convA(0);                // vmcnt waits pfA only; pfB stays outstanding
    issueA(2);
    asm volatile("s_waitcnt lgkmcnt(0)" ::: "memory");
    __builtin_amdgcn_s_barrier();
    __builtin_amdgcn_sched_barrier(0);

    for (int k = 0; k < NCHUNK; k += 2) {
        // consume chunk k from buf0; stage chunk k+1 (set B) into buf1
        convB(1);                                   // loads 2 iterations old
        if (k + 3 < NCHUNK) issueB(k + 3);
        mfma_phase(0);
        asm volatile("s_waitcnt lgkmcnt(0)" ::: "memory");
        __builtin_amdgcn_s_barrier();               // raw: vmcnt NOT drained
        __builtin_amdgcn_sched_barrier(0);

        // consume chunk k+1 from buf1; stage chunk k+2 (set A) into buf0
        if (k + 2 < NCHUNK) {
            convA(0);
            if (k + 4 < NCHUNK) issueA(k + 4);
        }
        mfma_phase(1);
        asm volatile("s_waitcnt lgkmcnt(0)" ::: "memory");
        __builtin_amdgcn_s_barrier();
        __builtin_amdgcn_sched_barrier(0);
    }

    // ---- epilogue ----
    #pragma unroll
    for (int i = 0; i < 4; ++i)
        atomicAdd(&S_lds[i * 32 + srow], psum[i]);

    #pragma unroll
    for (int m = 0; m < 2; ++m)
      #pragma unroll
      for (int n = 0; n < 4; ++n)
        #pragma unroll
        for (int e = 0; e < 4; ++e) {
            const int row = r0 + m * 16 + lg * 4 + e;
            const int col = c0 + n * 16 + ll;
            if (row == col) diag[row] = acc[m][n][e];
        }
    __syncthreads();

    if (tid < Cn) {
        const float S  = S_lds[tid];
        const float mu = S * (1.0f / Tn);
        float var = (diag[tid] - (float)Tn * mu * mu) * (1.0f / (Tn - 1));
        var = var < 0.f ? 0.f : var;
        const float sd = sqrtf(var);
        mrow[tid]  = mu;
        ivrow[tid] = 1.0f / (sd + 1e-8f);
        const size_t ofs = (size_t)Bn * Nn * Nn;
        out[ofs + (size_t)b * Nn + f * Cn + tid] = var;                      // node_features
        out[ofs + (size_t)Bn * Nn + ((size_t)b * Cn + tid) * Fn + f] = var;  // bandpowers
    }
    __syncthreads();

    // a = 0.5*(spa + |corr|) -> LDS A-tile (reuse smem); accumulate row sums
    float* At = (float*)smem;
    {
        float mi[2][4], ii[2][4], mj[4], ij[4];
        #pragma unroll
        for (int m = 0; m < 2; ++m)
          #pragma unroll
          for (int e = 0; e < 4; ++e) {
              const int row = r0 + m * 16 + lg * 4 + e;
              mi[m][e] = mrow[row];
              ii[m][e] = ivrow[row];
          }
        #pragma unroll
        for (int n = 0; n < 4; ++n) {
            const int col = c0 + n * 16 + ll;
            mj[n] = mrow[col];
            ij[n] = ivrow[col];
        }
        const float inv = 1.0f / (Tn - 1);
        #pragma unroll
        for (int m = 0; m < 2; ++m)
          #pragma unroll
          for (int e = 0; e < 4; ++e) {
              const int row = r0 + m * 16 + lg * 4 + e;
              float s = 0.f;
              #pragma unroll
              for (int n = 0; n < 4; ++n) {
                  const int col = c0 + n * 16 + ll;
                  float c = fabsf((acc[m][n][e] - (float)Tn * mi[m][e] * mj[n])
                                  * ii[m][e] * ij[n] * inv);
                  c = (row == col) ? 1.0f : c;
                  const int d = row > col ? row - col : col - row;
                  const float spa = (d >= 1 && d <= 3) ? 1.0f : 0.0f;
                  const float a = 0.5f * (spa + c);
                  At[row * Cn + col] = a;
                  s += a;
              }
              s += __shfl_xor(s, 1);
              s += __shfl_xor(s, 2);
              s += __shfl_xor(s, 4);
              s += __shfl_xor(s, 8);
              if (ll == 0) atomicAdd(&Dsum[row], s);
          }
    }
    __syncthreads();

    if (tid < Cn) dinv_s[tid] = rsqrtf(Dsum[tid] + 1e-8f);
    __syncthreads();

    // write full 128x640 stripe of A_norm (coalesced float4, zeros outside block)
    float* Ob = out + (size_t)b * Nn * Nn;
    const int fc = f * Cn;
    for (int e = 0; e < 40; ++e) {
        const int idx4 = e * 2048 + tid * 4;
        const int row = idx4 / Nn;
        const int col = idx4 - row * Nn;
        const int cl = col - fc;
        float4 v = {0.f, 0.f, 0.f, 0.f};
        if (cl >= 0 && cl < Cn) {
            const float dr = dinv_s[row];
            v.x = dr * At[row * Cn + cl]     * dinv_s[cl];
            v.y = dr * At[row * Cn + cl + 1] * dinv_s[cl + 1];
            v.z = dr * At[row * Cn + cl + 2] * dinv_s[cl + 2];
            v.w = dr * At[row * Cn + cl + 3] * dinv_s[cl + 3];
        }
        *(float4*)(Ob + (size_t)(fc + row) * Nn + col) = v;
    }
}

extern "C" void kernel_launch(void* const* d_in, const int* in_sizes, int n_in,
                              void* d_out, int out_size, void* d_ws, size_t ws_size,
                              hipStream_t stream) {
    const float* d0 = (const float*)d_in[0];
    const float* d1 = (const float*)d_in[1];
    const float* d2 = (const float*)d_in[2];
    const float* d3 = (const float*)d_in[3];
    const float* d4 = (const float*)d_in[4];
    float* out = (float*)d_out;

    strg_mono<<<dim3(Bn * Fn), dim3(512), 0, stream>>>(d0, d1, d2, d3, d4, out);
}